// Round 1
// baseline (348.527 us; speedup 1.0000x reference)
//
#include <hip/hip_runtime.h>

// MultiHeadSelfAttention: B=4, C=256, S=4096, heads=8, d=32.
// 3-kernel pipeline, all GEMMs on mfma_f32_16x16x32_bf16, fp32 accumulate.
//   k_qkv : qkv = x @ Wqkv^T + b  -> Qt (b,h,d,S) pre-scaled by scale*log2e,
//                                     K  (b,h,S,d), Vt (b,h,d,S)   [bf16]
//   k_attn: flash attention, fixed-max softmax (exp2, sum, divide) -> O (b,S,C) bf16
//   k_proj: out = O @ Wproj^T + b -> (B,C,S) fp32 via per-wave LDS transpose
// No barriers in any kernel (per-wave LDS regions; same-wave LDS is in-order).

typedef __attribute__((ext_vector_type(8))) short short8;  // 8 x bf16 MFMA frag
typedef __attribute__((ext_vector_type(4))) float f4;

__device__ __forceinline__ short f2bs(float f) {  // fp32 -> bf16 (RNE)
  union { float f; unsigned u; } v; v.f = f;
  unsigned r = v.u + 0x7FFFu + ((v.u >> 16) & 1u);
  return (short)(r >> 16);
}

__device__ __forceinline__ short8 cvt8(f4 a, f4 b) {
  short8 o;
  o[0] = f2bs(a[0]); o[1] = f2bs(a[1]); o[2] = f2bs(a[2]); o[3] = f2bs(a[3]);
  o[4] = f2bs(b[0]); o[5] = f2bs(b[1]); o[6] = f2bs(b[2]); o[7] = f2bs(b[3]);
  return o;
}

// ---------------------------------------------------------------- kernel 1
// D[j (768)][s] = sum_c Wqkv[j][c] * x[b][c][s]  (+bias later)
// A = Wqkv rows (direct 32B fp32 loads), B = x (8 coalesced scalar loads/frag).
// grid (256 m-tiles, 12 j-tiles), block 256 = 4 waves, wave = 16 j x 64 s.
__global__ __launch_bounds__(256) void k_qkv(
    const float* __restrict__ x, const float* __restrict__ w,
    const float* __restrict__ bias,
    short* __restrict__ Qt, short* __restrict__ Kq, short* __restrict__ Vt) {
  const int tid = threadIdx.x;
  const int L = tid & 63, wv = tid >> 6;
  const int ln15 = L & 15, quad = L >> 4;
  const int mt = blockIdx.x;
  const int b = mt >> 6;
  const int s0 = (mt & 63) << 6;
  const int j0 = blockIdx.y << 6;
  const int jw = j0 + wv * 16;

  f4 acc[4] = {{0,0,0,0},{0,0,0,0},{0,0,0,0},{0,0,0,0}};
  const float* wb = w + (jw + ln15) * 256 + quad * 8;
  const float* xb = x + b * (256 * 4096) + s0 + ln15;

#pragma unroll 2
  for (int cb = 0; cb < 256; cb += 32) {
    f4 a0 = *(const f4*)(wb + cb);
    f4 a1 = *(const f4*)(wb + cb + 4);
    short8 af = cvt8(a0, a1);
    const float* xc = xb + (cb + quad * 8) * 4096;
#pragma unroll
    for (int sub = 0; sub < 4; ++sub) {
      const float* xs = xc + sub * 16;
      short8 bf;
#pragma unroll
      for (int jj = 0; jj < 8; ++jj) bf[jj] = f2bs(xs[jj * 4096]);
      acc[sub] = __builtin_amdgcn_mfma_f32_16x16x32_bf16(af, bf, acc[sub], 0, 0, 0);
    }
  }

  float bj[4];
#pragma unroll
  for (int r = 0; r < 4; ++r) bj[r] = bias[jw + quad * 4 + r];

  const int type = j0 >> 8;  // 0=Q 1=K 2=V
  if (type == 0) {
    // Q -> Qt[(b*8+h)*32+d][s], fold in softmax scale * log2(e)
    const float qs = 0.17677669529663689f * 1.44269504088896f;
    const int h = jw >> 5;
    const int dbase = jw & 31;
#pragma unroll
    for (int r = 0; r < 4; ++r) {
      const int d = dbase + quad * 4 + r;
      short* qp = Qt + (size_t)((b * 8 + h) * 32 + d) * 4096 + s0 + ln15;
#pragma unroll
      for (int sub = 0; sub < 4; ++sub)
        qp[sub * 16] = f2bs((acc[sub][r] + bj[r]) * qs);
    }
  } else if (type == 2) {
    // V -> Vt[(b*8+h)*32+d][s]
    const int jv = jw - 512;
    const int h = jv >> 5;
    const int dbase = jv & 31;
#pragma unroll
    for (int r = 0; r < 4; ++r) {
      const int d = dbase + quad * 4 + r;
      short* vp = Vt + (size_t)((b * 8 + h) * 32 + d) * 4096 + s0 + ln15;
#pragma unroll
      for (int sub = 0; sub < 4; ++sub)
        vp[sub * 16] = f2bs(acc[sub][r] + bj[r]);
    }
  } else {
    // K: transpose 16j x 64s tile through per-wave LDS -> K[(b*8+h)*4096+s][d]
    __shared__ __align__(16) short tl[4 * 64 * 16];
    short* tw = tl + wv * 1024;
#pragma unroll
    for (int sub = 0; sub < 4; ++sub) {
      const int s = sub * 16 + ln15;
      const int swz = (s >> 2) & 1;
#pragma unroll
      for (int r = 0; r < 4; ++r) {
        const int dl = quad * 4 + r;
        tw[s * 16 + (((dl >> 3) ^ swz) * 8) + (dl & 7)] = f2bs(acc[sub][r] + bj[r]);
      }
    }
    const int h = (jw - 256) >> 5;
    const int d0 = (jw - 256) & 31;
#pragma unroll
    for (int i = 0; i < 2; ++i) {
      const int sl = i * 32 + (L >> 1);
      const int gg = L & 1;
      const int g2 = gg ^ ((sl >> 2) & 1);
      short8 row = *(const short8*)(tw + sl * 16 + g2 * 8);
      *(short8*)(Kq + (size_t)((b * 8 + h) * 4096 + s0 + sl) * 32 + d0 + gg * 8) = row;
    }
  }
}

// ---------------------------------------------------------------- kernel 2
// Flash attention, one wave = 32 queries, loop 64-key chunks.
// Fixed-max softmax: p = exp2(score'), score' prescaled into Q.
// P round-trips C-layout -> A-layout through swizzled per-wave LDS (no barriers).
__global__ __launch_bounds__(256) void k_attn(
    const short* __restrict__ Qt, const short* __restrict__ Kq,
    const short* __restrict__ Vt, short* __restrict__ O) {
  const int tid = threadIdx.x;
  const int L = tid & 63, wv = tid >> 6;
  const int ln15 = L & 15, quad = L >> 4;
  const int bh = blockIdx.y;  // same head across consecutive blocks -> L2 locality
  const int b = bh >> 3, h = bh & 7;
  const int qb = blockIdx.x * 128 + wv * 32;

  const short* Qb = Qt + (size_t)bh * 32 * 4096;
  const short* Kb = Kq + (size_t)bh * 4096 * 32;
  const short* Vb = Vt + (size_t)bh * 32 * 4096;

  __shared__ __align__(16) short plds[4 * 2048];  // 4 waves x (32q x 64k) bf16
  short* pw = plds + wv * 2048;

  // Q A-frags from Qt (strided scalar loads, once per wave)
  short8 qf[2];
#pragma unroll
  for (int qs = 0; qs < 2; ++qs)
#pragma unroll
    for (int jj = 0; jj < 8; ++jj)
      qf[qs][jj] = Qb[(quad * 8 + jj) * 4096 + qb + qs * 16 + ln15];

  f4 acc[2][2] = {{{0,0,0,0},{0,0,0,0}},{{0,0,0,0},{0,0,0,0}}};
  float lsum[2][4] = {{0,0,0,0},{0,0,0,0}};

  const int hb = ln15 >> 3, ln7 = ln15 & 7;
  const int swzr = ln15 >> 1;
  const short* kp = Kb + ln15 * 32 + quad * 8;
  const short* vp0 = Vb + ln15 * 4096 + quad * 8;
  const short* vp1 = vp0 + 16 * 4096;

#pragma unroll 2
  for (int kb = 0; kb < 4096; kb += 64) {
    // ---- S = Q K^T, exp2, stash P into LDS (swizzled)
#pragma unroll
    for (int t = 0; t < 4; ++t) {
      short8 kf = *(const short8*)(kp + (kb + t * 16) * 32);
#pragma unroll
      for (int qs = 0; qs < 2; ++qs) {
        f4 z = {0.f, 0.f, 0.f, 0.f};
        f4 sc = __builtin_amdgcn_mfma_f32_16x16x32_bf16(qf[qs], kf, z, 0, 0, 0);
#pragma unroll
        for (int r = 0; r < 4; ++r) {
          float p = __builtin_amdgcn_exp2f(sc[r]);
          lsum[qs][r] += p;
          const int gp = (t * 2 + hb) ^ (quad * 2 + (r >> 1));
          pw[(qs * 16 + quad * 4 + r) * 64 + gp * 8 + ln7] = f2bs(p);
        }
      }
    }
    // ---- O += P V
#pragma unroll
    for (int kk = 0; kk < 2; ++kk) {
      short8 vf0 = *(const short8*)(vp0 + kb + kk * 32);
      short8 vf1 = *(const short8*)(vp1 + kb + kk * 32);
#pragma unroll
      for (int qs = 0; qs < 2; ++qs) {
        const int gp = (kk * 4 + quad) ^ swzr;
        short8 pf = *(const short8*)(pw + (qs * 16 + ln15) * 64 + gp * 8);
        acc[qs][0] = __builtin_amdgcn_mfma_f32_16x16x32_bf16(pf, vf0, acc[qs][0], 0, 0, 0);
        acc[qs][1] = __builtin_amdgcn_mfma_f32_16x16x32_bf16(pf, vf1, acc[qs][1], 0, 0, 0);
      }
    }
  }

  // reduce l over the 16 lanes holding this row's keys, normalize, store O (b,S,C)
#pragma unroll
  for (int qs = 0; qs < 2; ++qs)
#pragma unroll
    for (int r = 0; r < 4; ++r) {
      float l = lsum[qs][r];
      l += __shfl_xor(l, 1);
      l += __shfl_xor(l, 2);
      l += __shfl_xor(l, 4);
      l += __shfl_xor(l, 8);
      const float rl = 1.0f / l;
      const int sg = qb + qs * 16 + quad * 4 + r;
      short* op = O + (size_t)(b * 4096 + sg) * 256 + h * 32 + ln15;
      op[0]  = f2bs(acc[qs][0][r] * rl);
      op[16] = f2bs(acc[qs][1][r] * rl);
    }
}

// ---------------------------------------------------------------- kernel 3
// out[b][c][s] = sum_j O[b][s][j] * Wproj[c][j] + bias[c]
// A = O (direct 16B bf16 frags), B = Wproj rows (direct 32B fp32 loads).
// Epilogue: per-wave LDS transpose 16s x 64c -> coalesced fp32 row stores.
__global__ __launch_bounds__(256) void k_proj(
    const short* __restrict__ O, const float* __restrict__ w,
    const float* __restrict__ bias, float* __restrict__ out) {
  const int tid = threadIdx.x;
  const int L = tid & 63, wv = tid >> 6;
  const int ln15 = L & 15, quad = L >> 4;
  const int m0 = blockIdx.x * 64 + wv * 16;
  const int n0 = blockIdx.y << 6;
  const int b = m0 >> 12, s0 = m0 & 4095;

  f4 acc[4] = {{0,0,0,0},{0,0,0,0},{0,0,0,0},{0,0,0,0}};
  const short* Ob = O + (size_t)(m0 + ln15) * 256 + quad * 8;
  const float* wb = w + (n0 + ln15) * 256 + quad * 8;

#pragma unroll 2
  for (int cb = 0; cb < 256; cb += 32) {
    short8 af = *(const short8*)(Ob + cb);
#pragma unroll
    for (int sub = 0; sub < 4; ++sub) {
      f4 b0 = *(const f4*)(wb + sub * (16 * 256) + cb);
      f4 b1 = *(const f4*)(wb + sub * (16 * 256) + cb + 4);
      short8 bf = cvt8(b0, b1);
      acc[sub] = __builtin_amdgcn_mfma_f32_16x16x32_bf16(af, bf, acc[sub], 0, 0, 0);
    }
  }

  __shared__ float tl[4][64 * 17];  // per-wave 64c x 16m fp32, stride 17
  float* tw = tl[wv];
#pragma unroll
  for (int sub = 0; sub < 4; ++sub) {
    const float bv = bias[n0 + sub * 16 + ln15];
#pragma unroll
    for (int r = 0; r < 4; ++r)
      tw[(sub * 16 + ln15) * 17 + quad * 4 + r] = acc[sub][r] + bv;
  }
#pragma unroll
  for (int i = 0; i < 4; ++i) {
    const int c = i * 16 + (L >> 2);
    const int ms = (L & 3) * 4;
    f4 v;
#pragma unroll
    for (int j = 0; j < 4; ++j) v[j] = tw[c * 17 + ms + j];
    *(f4*)(out + (size_t)b * (256 * 4096) + (size_t)(n0 + c) * 4096 + s0 + ms) = v;
  }
}

// ---------------------------------------------------------------- launcher
extern "C" void kernel_launch(void* const* d_in, const int* in_sizes, int n_in,
                              void* d_out, int out_size, void* d_ws, size_t ws_size,
                              hipStream_t stream) {
  const float* x      = (const float*)d_in[0];
  const float* w_qkv  = (const float*)d_in[1];
  const float* b_qkv  = (const float*)d_in[2];
  const float* w_proj = (const float*)d_in[3];
  const float* b_proj = (const float*)d_in[4];
  float* out = (float*)d_out;

  const size_t SEG = (size_t)4 * 8 * 4096 * 32;  // 4.19M bf16 elems = 8 MiB
  short* Qt = (short*)d_ws;
  short* Kq = Qt + SEG;
  short* Vt = Kq + SEG;
  short* O  = Vt + SEG;  // (B,S,C) bf16

  k_qkv <<<dim3(256, 12), 256, 0, stream>>>(x, w_qkv, b_qkv, Qt, Kq, Vt);
  k_attn<<<dim3(32, 32),  256, 0, stream>>>(Qt, Kq, Vt, O);
  k_proj<<<dim3(256, 4),  256, 0, stream>>>(O, w_proj, b_proj, out);
}